// Round 1
// baseline (83.448 us; speedup 1.0000x reference)
//
#include <hip/hip_runtime.h>
#include <math.h>

#ifndef M_PI
#define M_PI 3.14159265358979323846
#endif

// Original (pre-transpose) JPEG luma quant table, row-major.
// Reference uses the TRANSPOSE: qt_y(u,v) = YQ[v*8+u].
__device__ const float YQ[64] = {
    16.f, 11.f, 10.f, 16.f,  24.f,  40.f,  51.f,  61.f,
    12.f, 12.f, 14.f, 19.f,  26.f,  58.f,  60.f,  55.f,
    14.f, 13.f, 16.f, 24.f,  40.f,  57.f,  69.f,  56.f,
    14.f, 17.f, 22.f, 29.f,  51.f,  87.f,  80.f,  62.f,
    18.f, 22.f, 37.f, 56.f,  68.f, 109.f, 103.f,  77.f,
    24.f, 35.f, 55.f, 64.f,  81.f, 104.f, 113.f,  92.f,
    49.f, 64.f, 78.f, 87.f, 103.f, 121.f, 120.f, 101.f,
    72.f, 92.f, 95.f, 98.f, 112.f, 100.f, 103.f,  99.f
};

// Chroma quant table (symmetric, so transpose == itself).
__device__ const float CQ[64] = {
    17.f, 18.f, 24.f, 47.f, 99.f, 99.f, 99.f, 99.f,
    18.f, 21.f, 26.f, 66.f, 99.f, 99.f, 99.f, 99.f,
    24.f, 26.f, 56.f, 99.f, 99.f, 99.f, 99.f, 99.f,
    47.f, 66.f, 99.f, 99.f, 99.f, 99.f, 99.f, 99.f,
    99.f, 99.f, 99.f, 99.f, 99.f, 99.f, 99.f, 99.f,
    99.f, 99.f, 99.f, 99.f, 99.f, 99.f, 99.f, 99.f,
    99.f, 99.f, 99.f, 99.f, 99.f, 99.f, 99.f, 99.f,
    99.f, 99.f, 99.f, 99.f, 99.f, 99.f, 99.f, 99.f
};

// Tile: 64 wide x 32 tall pixels per workgroup (256 threads).
// LDS planes padded to stride 65 -> every pass is <=2-way bank aliasing (free).
#define TW 64
#define TH 32
#define LDSW 65

__global__ __launch_bounds__(256) void diffjpeg_kernel(const float* __restrict__ in,
                                                       float* __restrict__ out)
{
    __shared__ float pl[3][TH][LDSW];   // YCbCr*255-128 planes (in-place transformed)
    __shared__ float Cm[8][8];          // separable DCT matrix: Cm[u][x] = 0.5*a_u*cos((2x+1)u*pi/16)

    const int t = threadIdx.x;
    if (t < 64) {
        const int u = t >> 3, x = t & 7;
        const double au = (u == 0) ? 0.70710678118654752440 : 1.0;
        Cm[u][x] = (float)(0.5 * au * cos((2.0 * x + 1.0) * (double)u * M_PI / 16.0));
    }

    const int bid  = blockIdx.x;
    const int img  = bid >> 7;      // 128 tiles per image (16 rows x 8 cols)
    const int rem  = bid & 127;
    const int trow = rem >> 3;      // 0..15
    const int tcol = rem & 7;       // 0..7
    const size_t HW = (size_t)512 * 512;
    const size_t tbase = (size_t)img * 3 * HW + (size_t)(trow * TH) * 512 + (size_t)(tcol * TW);
    const float* __restrict__ pin  = in  + tbase;
    float* __restrict__       pout = out + tbase;

    // ---- Load + RGB->YCbCr (coalesced float4) ----
    #pragma unroll
    for (int i = 0; i < 2; ++i) {
        const int pix = i * 1024 + t * 4;
        const int row = pix >> 6;
        const int col = pix & 63;
        const float4 r4 = *(const float4*)(pin +            (size_t)row * 512 + col);
        const float4 g4 = *(const float4*)(pin + HW +       (size_t)row * 512 + col);
        const float4 b4 = *(const float4*)(pin + 2 * HW +   (size_t)row * 512 + col);
        const float* rp = (const float*)&r4;
        const float* gp = (const float*)&g4;
        const float* bp = (const float*)&b4;
        #pragma unroll
        for (int k = 0; k < 4; ++k) {
            const float r = fminf(fmaxf(rp[k], 0.f), 1.f);
            const float g = fminf(fmaxf(gp[k], 0.f), 1.f);
            const float b = fminf(fmaxf(bp[k], 0.f), 1.f);
            const float y  = 0.299f * r + 0.587f * g + 0.114f * b;
            const float cb = (b - y) * 0.564f + 0.5f;
            const float cr = (r - y) * 0.713f + 0.5f;
            pl[0][row][col + k] = y  * 255.f - 128.f;
            pl[1][row][col + k] = cb * 255.f - 128.f;
            pl[2][row][col + k] = cr * 255.f - 128.f;
        }
    }
    __syncthreads();

    // ---- Stage 1: column DCT (T1 = C * X), in-place per column ----
    {
        const int col = t & 63;
        const int br  = t >> 6;     // block-row 0..3
        for (int c = 0; c < 3; ++c) {
            float X[8], T[8];
            #pragma unroll
            for (int x = 0; x < 8; ++x) X[x] = pl[c][br * 8 + x][col];
            #pragma unroll
            for (int u = 0; u < 8; ++u) {
                float s = 0.f;
                #pragma unroll
                for (int x = 0; x < 8; ++x) s += Cm[u][x] * X[x];
                T[u] = s;
            }
            #pragma unroll
            for (int u = 0; u < 8; ++u) pl[c][br * 8 + u][col] = T[u];
        }
    }
    __syncthreads();

    // ---- Stage 2 (rows, fused): row DCT + quant/round/dequant + row IDCT ----
    {
        const int bc  = t & 7;          // block-col 0..7
        const int u   = (t >> 3) & 7;   // within-block row 0..7
        const int br  = t >> 6;         // block-row 0..3
        const int row = br * 8 + u;
        const int c0  = bc * 8;
        for (int c = 0; c < 3; ++c) {
            float T[8];
            #pragma unroll
            for (int y = 0; y < 8; ++y) T[y] = pl[c][row][c0 + y];
            float Dq[8];
            #pragma unroll
            for (int v = 0; v < 8; ++v) {
                float s = 0.f;
                #pragma unroll
                for (int y = 0; y < 8; ++y) s += Cm[v][y] * T[y];
                // reference quant: qte[c][u][v]; Y table is transposed, C is symmetric
                const float qt = (c == 0) ? YQ[v * 8 + u] : CQ[u * 8 + v];
                const float q  = s / qt;             // true division, like reference
                Dq[v] = rintf(q) * qt;               // round-half-even, exact forward
            }
            #pragma unroll
            for (int y = 0; y < 8; ++y) {
                float s = 0.f;
                #pragma unroll
                for (int v = 0; v < 8; ++v) s += Dq[v] * Cm[v][y];
                pl[c][row][c0 + y] = s;
            }
        }
    }
    __syncthreads();

    // ---- Stage 3: column IDCT (S = C^T * T2) + (x+128)/255, in-place ----
    {
        const int col = t & 63;
        const int br  = t >> 6;
        for (int c = 0; c < 3; ++c) {
            float X[8], S[8];
            #pragma unroll
            for (int u = 0; u < 8; ++u) X[u] = pl[c][br * 8 + u][col];
            #pragma unroll
            for (int x = 0; x < 8; ++x) {
                float s = 0.f;
                #pragma unroll
                for (int u = 0; u < 8; ++u) s += Cm[u][x] * X[u];
                S[x] = (s + 128.f) / 255.f;
            }
            #pragma unroll
            for (int x = 0; x < 8; ++x) pl[c][br * 8 + x][col] = S[x];
        }
    }
    __syncthreads();

    // ---- YCbCr->RGB + clip + coalesced float4 store ----
    #pragma unroll
    for (int i = 0; i < 2; ++i) {
        const int pix = i * 1024 + t * 4;
        const int row = pix >> 6;
        const int col = pix & 63;
        float4 r4, g4, b4;
        float* rp = (float*)&r4;
        float* gp = (float*)&g4;
        float* bp = (float*)&b4;
        #pragma unroll
        for (int k = 0; k < 4; ++k) {
            const float yy = pl[0][row][col + k];
            const float cb = pl[1][row][col + k] - 0.5f;
            const float cr = pl[2][row][col + k] - 0.5f;
            float rr = yy + 1.403f * cr;
            float gg = yy - 0.714f * cr - 0.344f * cb;
            float bb = yy + 1.773f * cb;
            rp[k] = fminf(fmaxf(rr, 0.f), 1.f);
            gp[k] = fminf(fmaxf(gg, 0.f), 1.f);
            bp[k] = fminf(fmaxf(bb, 0.f), 1.f);
        }
        *(float4*)(pout +          (size_t)row * 512 + col) = r4;
        *(float4*)(pout + HW +     (size_t)row * 512 + col) = g4;
        *(float4*)(pout + 2 * HW + (size_t)row * 512 + col) = b4;
    }
}

extern "C" void kernel_launch(void* const* d_in, const int* in_sizes, int n_in,
                              void* d_out, int out_size, void* d_ws, size_t ws_size,
                              hipStream_t stream) {
    const float* in = (const float*)d_in[0];
    float* out = (float*)d_out;
    const int B = in_sizes[0] / (3 * 512 * 512);   // 32
    const int grid = B * 128;                       // 128 tiles per image
    diffjpeg_kernel<<<grid, 256, 0, stream>>>(in, out);
}

// Round 2
// 42.081 us; speedup vs baseline: 1.9830x; 1.9830x over previous
//
#include <hip/hip_runtime.h>

// Separable DCT matrix, compile-time literals: CM[u][x] = 0.5*a_u*cos((2x+1)u*pi/16)
// (folds to inline constants after full unroll -> no VGPR/LDS cost)
static constexpr float CM[8][8] = {
    { 0.353553391f,  0.353553391f,  0.353553391f,  0.353553391f,  0.353553391f,  0.353553391f,  0.353553391f,  0.353553391f},
    { 0.490392640f,  0.415734806f,  0.277785117f,  0.097545161f, -0.097545161f, -0.277785117f, -0.415734806f, -0.490392640f},
    { 0.461939766f,  0.191341716f, -0.191341716f, -0.461939766f, -0.461939766f, -0.191341716f,  0.191341716f,  0.461939766f},
    { 0.415734806f, -0.097545161f, -0.490392640f, -0.277785117f,  0.277785117f,  0.490392640f,  0.097545161f, -0.415734806f},
    { 0.353553391f, -0.353553391f, -0.353553391f,  0.353553391f,  0.353553391f, -0.353553391f, -0.353553391f,  0.353553391f},
    { 0.277785117f, -0.490392640f,  0.097545161f,  0.415734806f, -0.415734806f, -0.097545161f,  0.490392640f, -0.277785117f},
    { 0.191341716f, -0.461939766f,  0.461939766f, -0.191341716f, -0.191341716f,  0.461939766f, -0.461939766f,  0.191341716f},
    { 0.097545161f, -0.277785117f,  0.415734806f, -0.490392640f,  0.490392640f, -0.415734806f,  0.277785117f, -0.097545161f}
};

// Original (pre-transpose) JPEG luma quant table, row-major.
// Reference uses the TRANSPOSE: qt_y(u,v) = YQ[v*8+u].
__device__ const float YQ[64] = {
    16.f, 11.f, 10.f, 16.f,  24.f,  40.f,  51.f,  61.f,
    12.f, 12.f, 14.f, 19.f,  26.f,  58.f,  60.f,  55.f,
    14.f, 13.f, 16.f, 24.f,  40.f,  57.f,  69.f,  56.f,
    14.f, 17.f, 22.f, 29.f,  51.f,  87.f,  80.f,  62.f,
    18.f, 22.f, 37.f, 56.f,  68.f, 109.f, 103.f,  77.f,
    24.f, 35.f, 55.f, 64.f,  81.f, 104.f, 113.f,  92.f,
    49.f, 64.f, 78.f, 87.f, 103.f, 121.f, 120.f, 101.f,
    72.f, 92.f, 95.f, 98.f, 112.f, 100.f, 103.f,  99.f
};

// Chroma quant table (symmetric -> transpose == itself).
__device__ const float CQ[64] = {
    17.f, 18.f, 24.f, 47.f, 99.f, 99.f, 99.f, 99.f,
    18.f, 21.f, 26.f, 66.f, 99.f, 99.f, 99.f, 99.f,
    24.f, 26.f, 56.f, 99.f, 99.f, 99.f, 99.f, 99.f,
    47.f, 66.f, 99.f, 99.f, 99.f, 99.f, 99.f, 99.f,
    99.f, 99.f, 99.f, 99.f, 99.f, 99.f, 99.f, 99.f,
    99.f, 99.f, 99.f, 99.f, 99.f, 99.f, 99.f, 99.f,
    99.f, 99.f, 99.f, 99.f, 99.f, 99.f, 99.f, 99.f,
    99.f, 99.f, 99.f, 99.f, 99.f, 99.f, 99.f, 99.f
};

// Tile 64 wide x 32 tall, 256 threads. LDS stride 68 floats: rows 272B (16B-aligned
// for float4 row access) and 68 % 32 == 4 -> column (scalar) access is 2-way = free.
#define LDSW 68

__global__ __launch_bounds__(256, 6) void diffjpeg_kernel(const float* __restrict__ in,
                                                          float* __restrict__ out)
{
    __shared__ __align__(16) float pl[3][32][LDSW];   // 26112 B -> 6 blocks/CU

    const int t   = threadIdx.x;
    const int col = t & 63;
    const int br  = t >> 6;          // block-row 0..3 (each owns 8 image rows)

    const int bid  = blockIdx.x;
    const int img  = bid >> 7;       // 128 tiles per image (16 rows x 8 cols)
    const int rem  = bid & 127;
    const int trow = rem >> 3;
    const int tcol = rem & 7;
    const size_t HW = (size_t)512 * 512;
    const size_t tbase = (size_t)img * 3 * HW + (size_t)(trow * 32) * 512 + (size_t)(tcol * 64);
    const float* __restrict__ pin  = in  + tbase;
    float* __restrict__       pout = out + tbase;

    // ---- Phase A: column load (coalesced per row) + RGB->YCbCr + column DCT ----
    {
        const float* cbase = pin + (size_t)(br * 8) * 512 + col;
        float rv[8], gv[8], bv[8];
        #pragma unroll
        for (int x = 0; x < 8; ++x) rv[x] = cbase[(size_t)x * 512];
        #pragma unroll
        for (int x = 0; x < 8; ++x) gv[x] = cbase[HW + (size_t)x * 512];
        #pragma unroll
        for (int x = 0; x < 8; ++x) bv[x] = cbase[2 * HW + (size_t)x * 512];

        float yv[8], cbv[8], crv[8];
        #pragma unroll
        for (int x = 0; x < 8; ++x) {
            const float r = fminf(fmaxf(rv[x], 0.f), 1.f);
            const float g = fminf(fmaxf(gv[x], 0.f), 1.f);
            const float b = fminf(fmaxf(bv[x], 0.f), 1.f);
            const float y  = 0.299f * r + 0.587f * g + 0.114f * b;
            yv[x]  = y * 255.f - 128.f;
            cbv[x] = ((b - y) * 0.564f + 0.5f) * 255.f - 128.f;
            crv[x] = ((r - y) * 0.713f + 0.5f) * 255.f - 128.f;
        }

        #pragma unroll
        for (int u = 0; u < 8; ++u) {
            float sy = 0.f, scb = 0.f, scr = 0.f;
            #pragma unroll
            for (int x = 0; x < 8; ++x) {
                sy  += CM[u][x] * yv[x];
                scb += CM[u][x] * cbv[x];
                scr += CM[u][x] * crv[x];
            }
            pl[0][br * 8 + u][col] = sy;
            pl[1][br * 8 + u][col] = scb;
            pl[2][br * 8 + u][col] = scr;
        }
    }
    __syncthreads();

    // ---- Phase B (rows, float4): row DCT + quant/round/dequant + row IDCT ----
    {
        const int bc  = t & 7;          // block-col 0..7
        const int u   = (t >> 3) & 7;   // frequency row within block
        const int row = (t >> 6) * 8 + u;
        #pragma unroll
        for (int c = 0; c < 3; ++c) {
            float4* rp = (float4*)&pl[c][row][bc * 8];
            const float4 a0 = rp[0];
            const float4 a1 = rp[1];
            const float T[8] = {a0.x, a0.y, a0.z, a0.w, a1.x, a1.y, a1.z, a1.w};
            float Dq[8];
            #pragma unroll
            for (int v = 0; v < 8; ++v) {
                float s = 0.f;
                #pragma unroll
                for (int y = 0; y < 8; ++y) s += CM[v][y] * T[y];
                const float qt = (c == 0) ? YQ[v * 8 + u] : CQ[u * 8 + v];
                Dq[v] = rintf(s / qt) * qt;          // IEEE div + round-half-even
            }
            float4 o0, o1;
            float* op = (float*)&o0;
            #pragma unroll
            for (int y = 0; y < 8; ++y) {
                float s = 0.f;
                #pragma unroll
                for (int v = 0; v < 8; ++v) s += Dq[v] * CM[v][y];
                if (y < 4) op[y] = s; else ((float*)&o1)[y - 4] = s;
            }
            rp[0] = o0;
            rp[1] = o1;
        }
    }
    __syncthreads();

    // ---- Phase C: column IDCT + YCbCr->RGB + clip + coalesced store ----
    {
        float Xy[8], Xcb[8], Xcr[8];
        #pragma unroll
        for (int u = 0; u < 8; ++u) {
            Xy[u]  = pl[0][br * 8 + u][col];
            Xcb[u] = pl[1][br * 8 + u][col];
            Xcr[u] = pl[2][br * 8 + u][col];
        }
        float* obase = pout + (size_t)(br * 8) * 512 + col;
        constexpr float inv255 = 1.0f / 255.0f;
        #pragma unroll
        for (int x = 0; x < 8; ++x) {
            float sy = 0.f, scb = 0.f, scr = 0.f;
            #pragma unroll
            for (int u = 0; u < 8; ++u) {
                sy  += CM[u][x] * Xy[u];
                scb += CM[u][x] * Xcb[u];
                scr += CM[u][x] * Xcr[u];
            }
            const float yy = (sy  + 128.f) * inv255;
            const float cb = (scb + 128.f) * inv255 - 0.5f;
            const float cr = (scr + 128.f) * inv255 - 0.5f;
            const float rr = yy + 1.403f * cr;
            const float gg = yy - 0.714f * cr - 0.344f * cb;
            const float bb = yy + 1.773f * cb;
            obase[(size_t)x * 512]          = fminf(fmaxf(rr, 0.f), 1.f);
            obase[HW + (size_t)x * 512]     = fminf(fmaxf(gg, 0.f), 1.f);
            obase[2 * HW + (size_t)x * 512] = fminf(fmaxf(bb, 0.f), 1.f);
        }
    }
}

extern "C" void kernel_launch(void* const* d_in, const int* in_sizes, int n_in,
                              void* d_out, int out_size, void* d_ws, size_t ws_size,
                              hipStream_t stream) {
    const float* in = (const float*)d_in[0];
    float* out = (float*)d_out;
    const int B = in_sizes[0] / (3 * 512 * 512);   // 32
    const int grid = B * 128;                       // 128 tiles per image
    diffjpeg_kernel<<<grid, 256, 0, stream>>>(in, out);
}

// Round 3
// 37.376 us; speedup vs baseline: 2.2327x; 1.1259x over previous
//
#include <hip/hip_runtime.h>

// Separable DCT constants: C_u = 0.5*a_u*cos(u*pi/16 scale family)
#define K4 0.353553391f
#define K1 0.490392640f
#define K3 0.415734806f
#define K5 0.277785117f
#define K7 0.097545161f
#define K2 0.461939766f
#define K6 0.191341716f

// Reference quant: qt_y(u,v) = Yorig[v][u]. Stored here already transposed so
// row u is contiguous in v:  YQT[u*8+v] = Yorig[v][u].
__device__ __align__(16) const float YQT[64] = {
    16.f, 12.f, 14.f, 14.f,  18.f,  24.f,  49.f,  72.f,
    11.f, 12.f, 13.f, 17.f,  22.f,  35.f,  64.f,  92.f,
    10.f, 14.f, 16.f, 22.f,  37.f,  55.f,  78.f,  95.f,
    16.f, 19.f, 24.f, 29.f,  56.f,  64.f,  87.f,  98.f,
    24.f, 26.f, 40.f, 51.f,  68.f,  81.f, 103.f, 112.f,
    40.f, 58.f, 57.f, 87.f, 109.f, 104.f, 121.f, 100.f,
    51.f, 60.f, 69.f, 80.f, 103.f, 113.f, 120.f, 103.f,
    61.f, 55.f, 56.f, 62.f,  77.f,  92.f, 101.f,  99.f
};

// Chroma table is symmetric (transpose == itself).
__device__ __align__(16) const float CQ[64] = {
    17.f, 18.f, 24.f, 47.f, 99.f, 99.f, 99.f, 99.f,
    18.f, 21.f, 26.f, 66.f, 99.f, 99.f, 99.f, 99.f,
    24.f, 26.f, 56.f, 99.f, 99.f, 99.f, 99.f, 99.f,
    47.f, 66.f, 99.f, 99.f, 99.f, 99.f, 99.f, 99.f,
    99.f, 99.f, 99.f, 99.f, 99.f, 99.f, 99.f, 99.f,
    99.f, 99.f, 99.f, 99.f, 99.f, 99.f, 99.f, 99.f,
    99.f, 99.f, 99.f, 99.f, 99.f, 99.f, 99.f, 99.f,
    99.f, 99.f, 99.f, 99.f, 99.f, 99.f, 99.f, 99.f
};

// 8-point DCT-II (scaled), even/odd butterfly: 36 ops vs 64.
__device__ __forceinline__ void dct8(const float x[8], float X[8]) {
    const float a0 = x[0] + x[7], a1 = x[1] + x[6], a2 = x[2] + x[5], a3 = x[3] + x[4];
    const float d0 = x[0] - x[7], d1 = x[1] - x[6], d2 = x[2] - x[5], d3 = x[3] - x[4];
    const float e0 = a0 + a3, e1 = a1 + a2, f0 = a0 - a3, f1 = a1 - a2;
    X[0] = K4 * (e0 + e1);
    X[4] = K4 * (e0 - e1);
    X[2] = K2 * f0 + K6 * f1;
    X[6] = K6 * f0 - K2 * f1;
    X[1] = K1 * d0 + K3 * d1 + K5 * d2 + K7 * d3;
    X[3] = K3 * d0 - K7 * d1 - K1 * d2 - K5 * d3;
    X[5] = K5 * d0 - K1 * d1 + K7 * d2 + K3 * d3;
    X[7] = K7 * d0 - K5 * d1 + K3 * d2 - K1 * d3;
}

// 8-point inverse (transpose) butterfly.
__device__ __forceinline__ void idct8(const float X[8], float x[8]) {
    const float g0 = K4 * (X[0] + X[4]);
    const float g1 = K4 * (X[0] - X[4]);
    const float E0 = g0 + K2 * X[2] + K6 * X[6];
    const float E1 = g1 + K6 * X[2] - K2 * X[6];
    const float E2 = g1 - K6 * X[2] + K2 * X[6];
    const float E3 = g0 - K2 * X[2] - K6 * X[6];
    const float O0 = K1 * X[1] + K3 * X[3] + K5 * X[5] + K7 * X[7];
    const float O1 = K3 * X[1] - K7 * X[3] - K1 * X[5] - K5 * X[7];
    const float O2 = K5 * X[1] - K1 * X[3] + K7 * X[5] + K3 * X[7];
    const float O3 = K7 * X[1] - K5 * X[3] + K3 * X[5] - K1 * X[7];
    x[0] = E0 + O0;  x[7] = E0 - O0;
    x[1] = E1 + O1;  x[6] = E1 - O1;
    x[2] = E2 + O2;  x[5] = E2 - O2;
    x[3] = E3 + O3;  x[4] = E3 - O3;
}

// Wave-local LDS fence: DS ops from one wave complete in order; lgkmcnt(0)
// guarantees prior ds_writes are visible to this wave's subsequent ds_reads.
// "memory" clobber stops the compiler reordering/caching LDS accesses.
__device__ __forceinline__ void wave_lds_fence() {
    asm volatile("s_waitcnt lgkmcnt(0)" ::: "memory");
}

// Tile 64x32 per 256-thread block; each WAVE independently owns a 64x8 strip
// (8 complete 8x8 blocks) -> no __syncthreads anywhere.
#define LDSW 68   // 272B rows: 16B-aligned for float4, bank-balanced for both passes

__global__ __launch_bounds__(256, 6) void diffjpeg_kernel(const float* __restrict__ in,
                                                          float* __restrict__ out)
{
    __shared__ __align__(16) float pl[3][32][LDSW];   // 26112 B -> 6 blocks/CU

    const int t  = threadIdx.x;
    const int l  = t & 63;      // lane = tile column
    const int wv = t >> 6;      // wave = strip (block-row)
    const int r0 = wv * 8;      // LDS row base of this wave's strip

    const int bid  = blockIdx.x;
    const int img  = bid >> 7;       // 128 tiles per image
    const int rem  = bid & 127;
    const int trow = rem >> 3;
    const int tcol = rem & 7;
    const size_t HW = (size_t)512 * 512;
    const size_t sbase = (size_t)img * 3 * HW + (size_t)(trow * 32 + wv * 8) * 512 + (size_t)(tcol * 64);
    const float* __restrict__ pin  = in  + sbase;   // this wave's strip base
    float* __restrict__       pout = out + sbase;

    // ---- Phase A: load strip column + RGB->YCbCr(255-scale) + column DCT ----
    {
        const float* cb = pin + l;
        float rv[8], gv[8], bv[8];
        #pragma unroll
        for (int x = 0; x < 8; ++x) rv[x] = cb[(size_t)x * 512];
        #pragma unroll
        for (int x = 0; x < 8; ++x) gv[x] = cb[HW + (size_t)x * 512];
        #pragma unroll
        for (int x = 0; x < 8; ++x) bv[x] = cb[2 * HW + (size_t)x * 512];

        float yv[8], cbv[8], crv[8];
        #pragma unroll
        for (int x = 0; x < 8; ++x) {
            const float r = fminf(fmaxf(rv[x], 0.f), 1.f);
            const float g = fminf(fmaxf(gv[x], 0.f), 1.f);
            const float b = fminf(fmaxf(bv[x], 0.f), 1.f);
            const float Y = fmaf(76.245f, r, fmaf(149.685f, g, 29.07f * b));  // 255*y
            yv[x]  = Y - 128.f;
            cbv[x] = fmaf(0.564f, fmaf(255.f, b, -Y), -0.5f);   // 255*cb - 128
            crv[x] = fmaf(0.713f, fmaf(255.f, r, -Y), -0.5f);   // 255*cr - 128
        }

        float X0[8], X1[8], X2[8];
        dct8(yv,  X0);
        dct8(cbv, X1);
        dct8(crv, X2);
        #pragma unroll
        for (int u = 0; u < 8; ++u) {
            pl[0][r0 + u][l] = X0[u];
            pl[1][r0 + u][l] = X1[u];
            pl[2][r0 + u][l] = X2[u];
        }
    }
    wave_lds_fence();

    // ---- Phase B: per-lane one row (freq u) of one block: row DCT + Q + row IDCT ----
    {
        const int b8 = (l >> 3) * 8;    // block's column offset in strip
        const int rr = l & 7;           // frequency row u

        const float4* yq4 = (const float4*)&YQT[rr * 8];
        const float4* cq4 = (const float4*)&CQ[rr * 8];
        const float4 yqa = yq4[0], yqb = yq4[1];
        const float4 cqa = cq4[0], cqb = cq4[1];
        const float yq[8] = {yqa.x, yqa.y, yqa.z, yqa.w, yqb.x, yqb.y, yqb.z, yqb.w};
        const float cq[8] = {cqa.x, cqa.y, cqa.z, cqa.w, cqb.x, cqb.y, cqb.z, cqb.w};

        #pragma unroll
        for (int c = 0; c < 3; ++c) {
            float4* rp = (float4*)&pl[c][r0 + rr][b8];
            const float4 a0 = rp[0];
            const float4 a1 = rp[1];
            const float T[8] = {a0.x, a0.y, a0.z, a0.w, a1.x, a1.y, a1.z, a1.w};
            float S[8];
            dct8(T, S);
            float Dq[8];
            #pragma unroll
            for (int v = 0; v < 8; ++v) {
                const float qt = (c == 0) ? yq[v] : cq[v];
                Dq[v] = rintf(S[v] / qt) * qt;    // IEEE div + round-half-even
            }
            float o[8];
            idct8(Dq, o);
            rp[0] = make_float4(o[0], o[1], o[2], o[3]);
            rp[1] = make_float4(o[4], o[5], o[6], o[7]);
        }
    }
    wave_lds_fence();

    // ---- Phase C: column IDCT + YCbCr->RGB + clip + nontemporal store ----
    {
        float Xy[8], Xcb[8], Xcr[8];
        #pragma unroll
        for (int u = 0; u < 8; ++u) {
            Xy[u]  = pl[0][r0 + u][l];
            Xcb[u] = pl[1][r0 + u][l];
            Xcr[u] = pl[2][r0 + u][l];
        }
        float sy[8], scb[8], scr[8];
        idct8(Xy,  sy);
        idct8(Xcb, scb);
        idct8(Xcr, scr);

        float* ob = pout + l;
        constexpr float inv255 = 1.0f / 255.0f;
        constexpr float Kr = 0.504711754f;   // 128/255 + 1.403*(128/255 - 0.5)
        constexpr float Kg = 0.499886280f;   // 128/255 - 1.058*(128/255 - 0.5)
        constexpr float Kb = 0.505437240f;   // 128/255 + 1.773*(128/255 - 0.5)
        #pragma unroll
        for (int x = 0; x < 8; ++x) {
            const float rr = fmaf(inv255, fmaf(1.403f, scr[x], sy[x]), Kr);
            const float tg = fmaf(-0.714f, scr[x], fmaf(-0.344f, scb[x], sy[x]));
            const float gg = fmaf(inv255, tg, Kg);
            const float bb = fmaf(inv255, fmaf(1.773f, scb[x], sy[x]), Kb);
            __builtin_nontemporal_store(fminf(fmaxf(rr, 0.f), 1.f), ob + (size_t)x * 512);
            __builtin_nontemporal_store(fminf(fmaxf(gg, 0.f), 1.f), ob + HW + (size_t)x * 512);
            __builtin_nontemporal_store(fminf(fmaxf(bb, 0.f), 1.f), ob + 2 * HW + (size_t)x * 512);
        }
    }
}

extern "C" void kernel_launch(void* const* d_in, const int* in_sizes, int n_in,
                              void* d_out, int out_size, void* d_ws, size_t ws_size,
                              hipStream_t stream) {
    const float* in = (const float*)d_in[0];
    float* out = (float*)d_out;
    const int B = in_sizes[0] / (3 * 512 * 512);   // 32
    const int grid = B * 128;                       // 128 tiles per image
    diffjpeg_kernel<<<grid, 256, 0, stream>>>(in, out);
}

// Round 4
// 35.499 us; speedup vs baseline: 2.3507x; 1.0529x over previous
//
#include <hip/hip_runtime.h>

typedef float f32x2 __attribute__((ext_vector_type(2)));

// Separable DCT constants
#define K4 0.353553391f
#define K1 0.490392640f
#define K3 0.415734806f
#define K5 0.277785117f
#define K7 0.097545161f
#define K2 0.461939766f
#define K6 0.191341716f

// Reference quant: qt_y(u,v) = Yorig[v][u]; stored transposed so row u is contiguous in v.
__device__ __align__(16) const float YQT[64] = {
    16.f, 12.f, 14.f, 14.f,  18.f,  24.f,  49.f,  72.f,
    11.f, 12.f, 13.f, 17.f,  22.f,  35.f,  64.f,  92.f,
    10.f, 14.f, 16.f, 22.f,  37.f,  55.f,  78.f,  95.f,
    16.f, 19.f, 24.f, 29.f,  56.f,  64.f,  87.f,  98.f,
    24.f, 26.f, 40.f, 51.f,  68.f,  81.f, 103.f, 112.f,
    40.f, 58.f, 57.f, 87.f, 109.f, 104.f, 121.f, 100.f,
    51.f, 60.f, 69.f, 80.f, 103.f, 113.f, 120.f, 103.f,
    61.f, 55.f, 56.f, 62.f,  77.f,  92.f, 101.f,  99.f
};
// Correctly-rounded reciprocals (compile-time IEEE division), same layout.
__device__ __align__(16) const float RYQT[64] = {
    1.f/16.f, 1.f/12.f, 1.f/14.f, 1.f/14.f, 1.f/18.f,  1.f/24.f,  1.f/49.f,  1.f/72.f,
    1.f/11.f, 1.f/12.f, 1.f/13.f, 1.f/17.f, 1.f/22.f,  1.f/35.f,  1.f/64.f,  1.f/92.f,
    1.f/10.f, 1.f/14.f, 1.f/16.f, 1.f/22.f, 1.f/37.f,  1.f/55.f,  1.f/78.f,  1.f/95.f,
    1.f/16.f, 1.f/19.f, 1.f/24.f, 1.f/29.f, 1.f/56.f,  1.f/64.f,  1.f/87.f,  1.f/98.f,
    1.f/24.f, 1.f/26.f, 1.f/40.f, 1.f/51.f, 1.f/68.f,  1.f/81.f,  1.f/103.f, 1.f/112.f,
    1.f/40.f, 1.f/58.f, 1.f/57.f, 1.f/87.f, 1.f/109.f, 1.f/104.f, 1.f/121.f, 1.f/100.f,
    1.f/51.f, 1.f/60.f, 1.f/69.f, 1.f/80.f, 1.f/103.f, 1.f/113.f, 1.f/120.f, 1.f/103.f,
    1.f/61.f, 1.f/55.f, 1.f/56.f, 1.f/62.f, 1.f/77.f,  1.f/92.f,  1.f/101.f, 1.f/99.f
};
// Chroma table (symmetric) + reciprocals.
__device__ __align__(16) const float CQ[64] = {
    17.f, 18.f, 24.f, 47.f, 99.f, 99.f, 99.f, 99.f,
    18.f, 21.f, 26.f, 66.f, 99.f, 99.f, 99.f, 99.f,
    24.f, 26.f, 56.f, 99.f, 99.f, 99.f, 99.f, 99.f,
    47.f, 66.f, 99.f, 99.f, 99.f, 99.f, 99.f, 99.f,
    99.f, 99.f, 99.f, 99.f, 99.f, 99.f, 99.f, 99.f,
    99.f, 99.f, 99.f, 99.f, 99.f, 99.f, 99.f, 99.f,
    99.f, 99.f, 99.f, 99.f, 99.f, 99.f, 99.f, 99.f,
    99.f, 99.f, 99.f, 99.f, 99.f, 99.f, 99.f, 99.f
};
__device__ __align__(16) const float RCQ[64] = {
    1.f/17.f, 1.f/18.f, 1.f/24.f, 1.f/47.f, 1.f/99.f, 1.f/99.f, 1.f/99.f, 1.f/99.f,
    1.f/18.f, 1.f/21.f, 1.f/26.f, 1.f/66.f, 1.f/99.f, 1.f/99.f, 1.f/99.f, 1.f/99.f,
    1.f/24.f, 1.f/26.f, 1.f/56.f, 1.f/99.f, 1.f/99.f, 1.f/99.f, 1.f/99.f, 1.f/99.f,
    1.f/47.f, 1.f/66.f, 1.f/99.f, 1.f/99.f, 1.f/99.f, 1.f/99.f, 1.f/99.f, 1.f/99.f,
    1.f/99.f, 1.f/99.f, 1.f/99.f, 1.f/99.f, 1.f/99.f, 1.f/99.f, 1.f/99.f, 1.f/99.f,
    1.f/99.f, 1.f/99.f, 1.f/99.f, 1.f/99.f, 1.f/99.f, 1.f/99.f, 1.f/99.f, 1.f/99.f,
    1.f/99.f, 1.f/99.f, 1.f/99.f, 1.f/99.f, 1.f/99.f, 1.f/99.f, 1.f/99.f, 1.f/99.f,
    1.f/99.f, 1.f/99.f, 1.f/99.f, 1.f/99.f, 1.f/99.f, 1.f/99.f, 1.f/99.f, 1.f/99.f
};

// fma helpers: scalar -> v_fma_f32, f32x2 -> v_pk_fma_f32 (bit-identical per lane-half)
__device__ __forceinline__ float gfma(float a, float b, float c) { return fmaf(a, b, c); }
__device__ __forceinline__ f32x2 gfma(f32x2 a, f32x2 b, f32x2 c) { return __builtin_elementwise_fma(a, b, c); }
__device__ __forceinline__ f32x2 gfma(float a, f32x2 b, f32x2 c) { return __builtin_elementwise_fma((f32x2){a, a}, b, c); }

// 8-point DCT-II butterfly, explicit fma (matches left-assoc contraction of R3 build).
template <typename T>
__device__ __forceinline__ void dct8(const T x[8], T X[8]) {
    const T a0 = x[0] + x[7], a1 = x[1] + x[6], a2 = x[2] + x[5], a3 = x[3] + x[4];
    const T d0 = x[0] - x[7], d1 = x[1] - x[6], d2 = x[2] - x[5], d3 = x[3] - x[4];
    const T e0 = a0 + a3, e1 = a1 + a2, f0 = a0 - a3, f1 = a1 - a2;
    X[0] = K4 * (e0 + e1);
    X[4] = K4 * (e0 - e1);
    X[2] = gfma(K6, f1, K2 * f0);
    X[6] = gfma(-K2, f1, K6 * f0);
    X[1] = gfma(K7, d3, gfma(K5, d2, gfma(K3, d1, K1 * d0)));
    X[3] = gfma(-K5, d3, gfma(-K1, d2, gfma(-K7, d1, K3 * d0)));
    X[5] = gfma(K3, d3, gfma(K7, d2, gfma(-K1, d1, K5 * d0)));
    X[7] = gfma(-K1, d3, gfma(K3, d2, gfma(-K5, d1, K7 * d0)));
}

template <typename T>
__device__ __forceinline__ void idct8(const T X[8], T x[8]) {
    const T g0 = K4 * (X[0] + X[4]);
    const T g1 = K4 * (X[0] - X[4]);
    const T E0 = gfma(K6, X[6], gfma(K2, X[2], g0));
    const T E1 = gfma(-K2, X[6], gfma(K6, X[2], g1));
    const T E2 = gfma(K2, X[6], gfma(-K6, X[2], g1));
    const T E3 = gfma(-K6, X[6], gfma(-K2, X[2], g0));
    const T O0 = gfma(K7, X[7], gfma(K5, X[5], gfma(K3, X[3], K1 * X[1])));
    const T O1 = gfma(-K5, X[7], gfma(-K1, X[5], gfma(-K7, X[3], K3 * X[1])));
    const T O2 = gfma(K3, X[7], gfma(K7, X[5], gfma(-K1, X[3], K5 * X[1])));
    const T O3 = gfma(-K1, X[7], gfma(K3, X[5], gfma(-K5, X[3], K7 * X[1])));
    x[0] = E0 + O0;  x[7] = E0 - O0;
    x[1] = E1 + O1;  x[6] = E1 - O1;
    x[2] = E2 + O2;  x[5] = E2 - O2;
    x[3] = E3 + O3;  x[4] = E3 - O3;
}

// Exact RN(s/qt) via Markstein refinement with correctly-rounded constant reciprocal,
// then round-half-even and dequantize. Bit-identical to IEEE division + rintf.
__device__ __forceinline__ f32x2 quant2(f32x2 sv, f32x2 qt, f32x2 rq) {
    const f32x2 q0 = sv * rq;
    const f32x2 e  = gfma(-qt, q0, sv);
    const f32x2 q  = gfma(rq, e, q0);
    const f32x2 n  = {rintf(q.x), rintf(q.y)};
    return n * qt;
}

__device__ __forceinline__ void wave_lds_fence() {
    asm volatile("s_waitcnt lgkmcnt(0)" ::: "memory");
}

#define LDSW 68   // 272B rows: 16B-aligned for float4, 2-way-free banks both passes

__global__ __launch_bounds__(256, 6) void diffjpeg_kernel(const float* __restrict__ in,
                                                          float* __restrict__ out)
{
    __shared__ __align__(16) float pl[3][32][LDSW];   // 26112 B -> 6 blocks/CU

    const int t  = threadIdx.x;
    const int l  = t & 63;
    const int wv = t >> 6;
    const int r0 = wv * 8;

    const int bid  = blockIdx.x;
    const int img  = bid >> 7;
    const int rem  = bid & 127;
    const int trow = rem >> 3;
    const int tcol = rem & 7;
    const size_t HW = (size_t)512 * 512;
    const size_t sbase = (size_t)img * 3 * HW + (size_t)(trow * 32 + wv * 8) * 512 + (size_t)(tcol * 64);
    const float* __restrict__ pin  = in  + sbase;
    float* __restrict__       pout = out + sbase;

    // ---- Phase A: load strip column + RGB->YCbCr + column DCT (chroma packed) ----
    {
        const float* cb = pin + l;
        float rv[8], gv[8], bv[8];
        #pragma unroll
        for (int x = 0; x < 8; ++x) rv[x] = cb[(size_t)x * 512];
        #pragma unroll
        for (int x = 0; x < 8; ++x) gv[x] = cb[HW + (size_t)x * 512];
        #pragma unroll
        for (int x = 0; x < 8; ++x) bv[x] = cb[2 * HW + (size_t)x * 512];

        float yv[8];
        f32x2 cc[8];
        #pragma unroll
        for (int x = 0; x < 8; ++x) {
            const float r = fminf(fmaxf(rv[x], 0.f), 1.f);
            const float g = fminf(fmaxf(gv[x], 0.f), 1.f);
            const float b = fminf(fmaxf(bv[x], 0.f), 1.f);
            const float Y = fmaf(76.245f, r, fmaf(149.685f, g, 29.07f * b));  // 255*y
            yv[x] = Y - 128.f;
            const f32x2 tbr = gfma(255.f, (f32x2){b, r}, (f32x2){-Y, -Y});
            cc[x] = gfma((f32x2){0.564f, 0.713f}, tbr, (f32x2){-0.5f, -0.5f}); // {cb,cr}
        }

        float X0[8];
        f32x2 XC[8];
        dct8(yv, X0);
        dct8(cc, XC);
        #pragma unroll
        for (int u = 0; u < 8; ++u) {
            pl[0][r0 + u][l] = X0[u];
            pl[1][r0 + u][l] = XC[u].x;
            pl[2][r0 + u][l] = XC[u].y;
        }
    }
    wave_lds_fence();

    // ---- Phase B: per-lane one row: row DCT + quant/round/dequant + row IDCT ----
    {
        const int b8 = (l >> 3) * 8;
        const int rr = l & 7;

        const float4* yq4  = (const float4*)&YQT[rr * 8];
        const float4* ryq4 = (const float4*)&RYQT[rr * 8];
        const float4* cq4  = (const float4*)&CQ[rr * 8];
        const float4* rcq4 = (const float4*)&RCQ[rr * 8];
        const float4 yqa = yq4[0],  yqb = yq4[1];
        const float4 rya = ryq4[0], ryb = ryq4[1];
        const float4 cqa = cq4[0],  cqb = cq4[1];
        const float4 rca = rcq4[0], rcb4 = rcq4[1];
        const float yq[8]  = {yqa.x, yqa.y, yqa.z, yqa.w, yqb.x, yqb.y, yqb.z, yqb.w};
        const float ryq[8] = {rya.x, rya.y, rya.z, rya.w, ryb.x, ryb.y, ryb.z, ryb.w};
        const float cq[8]  = {cqa.x, cqa.y, cqa.z, cqa.w, cqb.x, cqb.y, cqb.z, cqb.w};
        const float rcq[8] = {rca.x, rca.y, rca.z, rca.w, rcb4.x, rcb4.y, rcb4.z, rcb4.w};

        // Y (scalar transform, packed pairwise quant)
        {
            float4* rp = (float4*)&pl[0][r0 + rr][b8];
            const float4 a0 = rp[0];
            const float4 a1 = rp[1];
            const float T[8] = {a0.x, a0.y, a0.z, a0.w, a1.x, a1.y, a1.z, a1.w};
            float S[8];
            dct8(T, S);
            float Dq[8];
            #pragma unroll
            for (int i = 0; i < 4; ++i) {
                const f32x2 d = quant2((f32x2){S[2*i], S[2*i+1]},
                                       (f32x2){yq[2*i], yq[2*i+1]},
                                       (f32x2){ryq[2*i], ryq[2*i+1]});
                Dq[2*i] = d.x; Dq[2*i+1] = d.y;
            }
            float o[8];
            idct8(Dq, o);
            rp[0] = make_float4(o[0], o[1], o[2], o[3]);
            rp[1] = make_float4(o[4], o[5], o[6], o[7]);
        }

        // Chroma (cb,cr) fully packed
        {
            float4* rpb = (float4*)&pl[1][r0 + rr][b8];
            float4* rpr = (float4*)&pl[2][r0 + rr][b8];
            const float4 c0 = rpb[0], c1 = rpb[1];
            const float4 e0 = rpr[0], e1 = rpr[1];
            const f32x2 T[8] = {{c0.x, e0.x}, {c0.y, e0.y}, {c0.z, e0.z}, {c0.w, e0.w},
                                {c1.x, e1.x}, {c1.y, e1.y}, {c1.z, e1.z}, {c1.w, e1.w}};
            f32x2 S[8];
            dct8(T, S);
            f32x2 Dq[8];
            #pragma unroll
            for (int v = 0; v < 8; ++v)
                Dq[v] = quant2(S[v], (f32x2){cq[v], cq[v]}, (f32x2){rcq[v], rcq[v]});
            f32x2 o[8];
            idct8(Dq, o);
            rpb[0] = make_float4(o[0].x, o[1].x, o[2].x, o[3].x);
            rpb[1] = make_float4(o[4].x, o[5].x, o[6].x, o[7].x);
            rpr[0] = make_float4(o[0].y, o[1].y, o[2].y, o[3].y);
            rpr[1] = make_float4(o[4].y, o[5].y, o[6].y, o[7].y);
        }
    }
    wave_lds_fence();

    // ---- Phase C: column IDCT (chroma packed) + YCbCr->RGB + clip + nt store ----
    {
        float Xy[8];
        f32x2 Xc[8];
        #pragma unroll
        for (int u = 0; u < 8; ++u) {
            Xy[u] = pl[0][r0 + u][l];
            Xc[u] = (f32x2){pl[1][r0 + u][l], pl[2][r0 + u][l]};
        }
        float sy[8];
        f32x2 sc[8];
        idct8(Xy, sy);
        idct8(Xc, sc);

        float* ob = pout + l;
        constexpr float inv255 = 1.0f / 255.0f;
        constexpr float Kr = 0.504711754f;
        constexpr float Kg = 0.499886280f;
        constexpr float Kb = 0.505437240f;
        #pragma unroll
        for (int x = 0; x < 8; ++x) {
            const float scb = sc[x].x;
            const float scr = sc[x].y;
            const f32x2 inner = gfma((f32x2){1.403f, 1.773f}, (f32x2){scr, scb},
                                     (f32x2){sy[x], sy[x]});
            const f32x2 rb = gfma(inv255, inner, (f32x2){Kr, Kb});
            const float gg = fmaf(inv255, fmaf(-0.714f, scr, fmaf(-0.344f, scb, sy[x])), Kg);
            __builtin_nontemporal_store(fminf(fmaxf(rb.x, 0.f), 1.f), ob + (size_t)x * 512);
            __builtin_nontemporal_store(fminf(fmaxf(gg,   0.f), 1.f), ob + HW + (size_t)x * 512);
            __builtin_nontemporal_store(fminf(fmaxf(rb.y, 0.f), 1.f), ob + 2 * HW + (size_t)x * 512);
        }
    }
}

extern "C" void kernel_launch(void* const* d_in, const int* in_sizes, int n_in,
                              void* d_out, int out_size, void* d_ws, size_t ws_size,
                              hipStream_t stream) {
    const float* in = (const float*)d_in[0];
    float* out = (float*)d_out;
    const int B = in_sizes[0] / (3 * 512 * 512);   // 32
    const int grid = B * 128;
    diffjpeg_kernel<<<grid, 256, 0, stream>>>(in, out);
}